// Round 9
// baseline (4288.457 us; speedup 1.0000x reference)
//
#include <hip/hip_runtime.h>

typedef __attribute__((ext_vector_type(8))) short short8;
typedef __attribute__((ext_vector_type(4))) float fx4;
typedef __attribute__((ext_vector_type(4))) int ix4;

#define MFMA16(a, b, c) __builtin_amdgcn_mfma_f32_16x16x32_bf16((a), (b), (c), 0, 0, 0)

__device__ __forceinline__ short f2bf(float f) {
  unsigned u = __float_as_uint(f);
  u += 0x7fffu + ((u >> 16) & 1u);
  return (short)(u >> 16);
}
__device__ __forceinline__ float bf2f(short v) {
  return __uint_as_float(((unsigned)(unsigned short)v) << 16);
}
__device__ __forceinline__ void glds16(const short* g, short* l) {
  __builtin_amdgcn_global_load_lds((const __attribute__((address_space(1))) void*)g,
                                   (__attribute__((address_space(3))) void*)l, 16, 0, 0);
}

// ---------- transpose + convert: W [K][N] f32 -> Wt [N][K] bf16 ----------
__global__ __launch_bounds__(256)
void transpose_cvt(const float* __restrict__ W, short* __restrict__ Wt, int K, int N) {
  __shared__ float tile[64][65];
  const int kb = blockIdx.x * 64, nb = blockIdx.y * 64;
  const int t = threadIdx.x;
  const int tr = t >> 6, tc = t & 63;
#pragma unroll 4
  for (int i = 0; i < 16; i++) {
    int r = i * 4 + tr;
    tile[r][tc] = W[(size_t)(kb + r) * N + nb + tc];
  }
  __syncthreads();
#pragma unroll 4
  for (int i = 0; i < 16; i++) {
    int r = i * 4 + tr;
    Wt[(size_t)(nb + r) * K + kb + tc] = f2bf(tile[tc][r]);
  }
}

// ---------- CPB MLP: t[row][h] = relu(rt[row] @ w1 + b1) @ w2 ----------
__global__ __launch_bounds__(256)
void cpb_kernel(const float* __restrict__ rt, const float* __restrict__ w1,
                const float* __restrict__ b1, const float* __restrict__ w2,
                float* __restrict__ tt) {
  const int id = blockIdx.x * 256 + threadIdx.x;
  if (id >= 2197 * 8) return;
  const int row = id >> 3, hh = id & 7;
  float r[8];
#pragma unroll
  for (int i = 0; i < 8; i++) r[i] = rt[row * 8 + i];
  float acc = 0.0f;
  for (int c = 0; c < 512; c++) {
    float s = b1[c];
#pragma unroll
    for (int i = 0; i < 8; i++) s += r[i] * w1[i * 512 + c];
    s = fmaxf(s, 0.0f);
    acc += s * w2[c * 8 + hh];
  }
  tt[id] = acc;
}

// ---------- bias -> MFMA-fragment layout, bf16, pre-masked with -1e30 ----
__global__ __launch_bounds__(256)
void build_biasfrag(const float* __restrict__ tt, const int* __restrict__ ridx,
                    short* __restrict__ biasb) {
  const int id = blockIdx.x * 256 + threadIdx.x;
  if (id >= 8 * 22 * 11 * 512) return;
  const int e = id & 7;
  const int lane = (id >> 3) & 63;
  const int rest = id >> 9;
  const int jp = rest % 11;
  const int rest2 = rest / 11;
  const int qt = rest2 % 22;
  const int h = rest2 / 22;
  const int q = qt * 16 + ((lane >> 4) << 2) + (e & 3);
  const int tok = (jp * 2 + (e >> 2)) * 16 + (lane & 15);
  float val = -1e30f;
  if (q < 343 && tok < 343) val = tt[ridx[q * 343 + tok] * 8 + h];
  biasb[id] = f2bf(val);
}

// ---------- LayerNorm: one wave per row of 512 ----------
template <bool BF16OUT>
__global__ __launch_bounds__(256)
void ln_kernel(const float* x, const float* __restrict__ g,
               const float* __restrict__ bb, void* out) {
  const int row = blockIdx.x * 4 + (threadIdx.x >> 6);
  const int lane = threadIdx.x & 63;
  const float* xr = x + (size_t)row * 512 + lane * 8;
  fx4 va = *(const fx4*)xr;
  fx4 vb = *(const fx4*)(xr + 4);
  float s = va[0] + va[1] + va[2] + va[3] + vb[0] + vb[1] + vb[2] + vb[3];
#pragma unroll
  for (int d = 1; d < 64; d <<= 1) s += __shfl_xor(s, d);
  const float mu = s * (1.0f / 512.0f);
  float v[8];
#pragma unroll
  for (int i = 0; i < 4; i++) { v[i] = va[i] - mu; v[4 + i] = vb[i] - mu; }
  float s2 = 0.0f;
#pragma unroll
  for (int i = 0; i < 8; i++) s2 += v[i] * v[i];
#pragma unroll
  for (int d = 1; d < 64; d <<= 1) s2 += __shfl_xor(s2, d);
  const float rs = rsqrtf(s2 * (1.0f / 512.0f) + 1e-5f);
  fx4 ga = *(const fx4*)(g + lane * 8);
  fx4 gb = *(const fx4*)(g + lane * 8 + 4);
  fx4 ba = *(const fx4*)(bb + lane * 8);
  fx4 b2 = *(const fx4*)(bb + lane * 8 + 4);
  float o[8];
#pragma unroll
  for (int i = 0; i < 4; i++) {
    o[i] = v[i] * rs * ga[i] + ba[i];
    o[4 + i] = v[4 + i] * rs * gb[i] + b2[i];
  }
  if (BF16OUT) {
    short8 ov;
#pragma unroll
    for (int i = 0; i < 8; i++) ov[i] = f2bf(o[i]);
    *(short8*)((short*)out + (size_t)row * 512 + lane * 8) = ov;
  } else {
    float* op = (float*)out + (size_t)row * 512 + lane * 8;
    fx4 o1, o2;
#pragma unroll
    for (int i = 0; i < 4; i++) { o1[i] = o[i]; o2[i] = o[4 + i]; }
    *(fx4*)op = o1;
    *(fx4*)(op + 4) = o2;
  }
}

// ---------- 128x128 bf16 GEMM, BK=32, 3-buffer counted-vmcnt pipeline ----
// T3/T4 minimum: prefetch depth 2; per K-step only `s_waitcnt vmcnt(4)`
// (own stage-k loads) + raw s_barrier -- stages k+1,k+2 stay IN FLIGHT
// across the barrier (no vmcnt(0) drain; that drain was the round-8 stall:
// MfmaUtil 18%, VALUBusy 11%, both idle). Safety: per-wave vmcnt BEFORE
// barrier covers cross-wave chunk reads; b[(k+2)%3] overwrite is fenced by
// the barrier after its readers' lgkm-waited MFMAs. st_16x32 swizzle kept.
// EPI 0: bf16 out, *0.125 where col<scaleN (fused QKV)
// EPI 1: f32 out = xres + acc                     (O-proj residual)
// EPI 2: bf16 out = gelu_tanh(acc + bias[col])    (FFN1, rcp-based)
// EPI 3: f32 out = xres + acc + bias[col]         (FFN2 residual)
template <int EPI>
__global__ __launch_bounds__(256, 3)
void gemm_s(const short* __restrict__ A, const short* __restrict__ Bt,
            int N, int K, int nbn, int scaleN,
            const float* __restrict__ bias, const float* xres, void* out) {
  __shared__ short Al[3][4096];  // 3 x [8 chunks][16r x 32c swizzled]
  __shared__ short Bl[3][4096];
  const int nwg = gridDim.x;
  const int orig = blockIdx.x;
  const int qq = nwg >> 3, rr = nwg & 7, xc = orig & 7, o8 = orig >> 3;
  const int wgid = (xc < rr ? xc * (qq + 1) : rr * (qq + 1) + (xc - rr) * qq) + o8;
  const int m0 = (wgid / nbn) * 128, n0 = (wgid % nbn) * 128;
  const int t = threadIdx.x, lane = t & 63, wv = t >> 6;
  const int wm = (wv >> 1) * 64, wn = (wv & 1) * 64;
  const int lr = lane & 15, lg = lane >> 4;
  // staging: wave wv owns chunks {2wv, 2wv+1} (rows wv*32 .. wv*32+32)
  const int scol = ((lane & 3) * 8) ^ ((lane & 32) ? 16 : 0);  // pre-swizzled src col
  const int srow = lane >> 2;                                  // 0..15 within chunk
  const short* ag0 = A + (size_t)(m0 + wv * 32 + srow) * K + scol;
  const short* ag1 = A + (size_t)(m0 + wv * 32 + 16 + srow) * K + scol;
  const short* bg0 = Bt + (size_t)(n0 + wv * 32 + srow) * K + scol;
  const short* bg1 = Bt + (size_t)(n0 + wv * 32 + 16 + srow) * K + scol;
  // fragment read offsets (swizzled): frag mi == chunk (wave_m*4+mi)
  const int cswz = (lg * 8) ^ ((lr & 8) ? 16 : 0);
  int aoff[4], boff[4];
#pragma unroll
  for (int i = 0; i < 4; i++) {
    aoff[i] = ((wv >> 1) * 4 + i) * 512 + lr * 32 + cswz;
    boff[i] = ((wv & 1) * 4 + i) * 512 + lr * 32 + cswz;
  }
  fx4 acc[4][4] = {};
#define STAGE(KT, BUF)                              \
  do {                                              \
    const int off_ = (KT) * 32;                     \
    short* la_ = &Al[BUF][wv * 1024];               \
    short* lb_ = &Bl[BUF][wv * 1024];               \
    glds16(ag0 + off_, la_);                        \
    glds16(ag1 + off_, la_ + 512);                  \
    glds16(bg0 + off_, lb_);                        \
    glds16(bg1 + off_, lb_ + 512);                  \
  } while (0)
  const int nkt = K >> 5;
  STAGE(0, 0);
  STAGE(1, 1);
  int rb = 0;  // read-buffer index, kt % 3
  for (int kt = 0; kt < nkt; kt++) {
    if (kt + 1 < nkt)
      asm volatile("s_waitcnt vmcnt(4)" ::: "memory");  // own stage-k loads done
    else
      asm volatile("s_waitcnt vmcnt(0)" ::: "memory");  // final drain
    __builtin_amdgcn_s_barrier();  // all waves' stage-k data now in LDS
    if (kt + 2 < nkt) {
      int sb = rb + 2;
      if (sb >= 3) sb -= 3;
      STAGE(kt + 2, sb);  // stays in flight across next barrier
    }
    short8 af[4], bf[4];
#pragma unroll
    for (int i = 0; i < 4; i++) af[i] = *(const short8*)&Al[rb][aoff[i]];
#pragma unroll
    for (int i = 0; i < 4; i++) bf[i] = *(const short8*)&Bl[rb][boff[i]];
#pragma unroll
    for (int mi = 0; mi < 4; mi++)
#pragma unroll
      for (int ni = 0; ni < 4; ni++)
        acc[mi][ni] = MFMA16(af[mi], bf[ni], acc[mi][ni]);
    rb = (rb + 1 < 3) ? rb + 1 : 0;
  }
#undef STAGE
#pragma unroll
  for (int mi = 0; mi < 4; mi++) {
#pragma unroll
    for (int ni = 0; ni < 4; ni++) {
#pragma unroll
      for (int r = 0; r < 4; r++) {
        const int row = m0 + wm + mi * 16 + lg * 4 + r;
        const int col = n0 + wn + ni * 16 + lr;
        const float vacc = acc[mi][ni][r];
        const size_t idx = (size_t)row * N + col;
        if (EPI == 0) {
          const float sc = (col < scaleN) ? 0.125f : 1.0f;
          ((short*)out)[idx] = f2bf(vacc * sc);
        } else if (EPI == 1) {
          ((float*)out)[idx] = xres[idx] + vacc;
        } else if (EPI == 2) {
          const float v = vacc + bias[col];
          const float tt = v * v;
          const float u2 = v * fmaf(tt, -0.0713548165f, -1.5957691216f);  // -2u
          const float g = v * __builtin_amdgcn_rcpf(1.0f + __expf(u2));
          ((short*)out)[idx] = f2bf(g);
        } else {
          ((float*)out)[idx] = xres[idx] + vacc + bias[col];
        }
      }
    }
  }
}

// ---------- fused windowed attention v3: block=(b,h), 512 thr, 8 waves ---
__global__ __launch_bounds__(512, 1)
void attn_kernel(const short* __restrict__ qkv, const short* __restrict__ biasb,
                 short* __restrict__ obuf) {
  __shared__ short Kl[352][72];
  __shared__ short Vt[64][360];
  __shared__ short Pl[8][16][96];
  const int b = blockIdx.x >> 3, h = blockIdx.x & 7;
  const int t = threadIdx.x, lane = t & 63, wv = t >> 6;
  const int lr = lane & 15, lg = lane >> 4;
  const size_t base = (size_t)b * 343 * 1536 + h * 64;
  const short* qg = qkv + base;
  const short* kg = qkv + base + 512;
  const short* vg = qkv + base + 1024;
  for (int c = t; c < 352 * 8; c += 512) {
    const int tok = c >> 3, d8 = (c & 7) * 8;
    const int ts = tok < 343 ? tok : 342;
    short8 kvv = *(const short8*)(kg + (size_t)ts * 1536 + d8);
    short8 vvv = *(const short8*)(vg + (size_t)ts * 1536 + d8);
    *(short8*)&Kl[tok][d8] = kvv;
#pragma unroll
    for (int j = 0; j < 8; j++) Vt[d8 + j][tok] = vvv[j];
  }
  __syncthreads();
  for (int qt = wv; qt < 22; qt += 8) {
    const int q0 = qt * 16;
    const int qr = q0 + lr;
    const int qs = qr < 343 ? qr : 342;
    short8 qf0 = *(const short8*)(qg + (size_t)qs * 1536 + lg * 8);
    short8 qf1 = *(const short8*)(qg + (size_t)qs * 1536 + 32 + lg * 8);
    fx4 s[22];
#pragma unroll
    for (int j = 0; j < 22; j++) {
      short8 kf0 = *(const short8*)&Kl[j * 16 + lr][lg * 8];
      short8 kf1 = *(const short8*)&Kl[j * 16 + lr][32 + lg * 8];
      fx4 z = {0.0f, 0.0f, 0.0f, 0.0f};
      z = MFMA16(qf0, kf0, z);
      z = MFMA16(qf1, kf1, z);
      s[j] = z;
    }
    const short* bp = biasb + (size_t)((h * 22 + qt) * 11) * 512 + lane * 8;
#pragma unroll
    for (int jp = 0; jp < 11; jp++) {
      short8 bb = *(const short8*)(bp + jp * 512);
#pragma unroll
      for (int r = 0; r < 4; r++) {
        s[2 * jp][r] += bf2f(bb[r]);
        s[2 * jp + 1][r] += bf2f(bb[4 + r]);
      }
    }
    float mx[4] = {-1e30f, -1e30f, -1e30f, -1e30f};
#pragma unroll
    for (int j = 0; j < 22; j++)
#pragma unroll
      for (int r = 0; r < 4; r++) mx[r] = fmaxf(mx[r], s[j][r]);
#pragma unroll
    for (int r = 0; r < 4; r++) {
      float m = mx[r];
      m = fmaxf(m, __shfl_xor(m, 1));
      m = fmaxf(m, __shfl_xor(m, 2));
      m = fmaxf(m, __shfl_xor(m, 4));
      m = fmaxf(m, __shfl_xor(m, 8));
      mx[r] = m;
    }
    float sm[4] = {0.0f, 0.0f, 0.0f, 0.0f};
#pragma unroll
    for (int j = 0; j < 22; j++)
#pragma unroll
      for (int r = 0; r < 4; r++) {
        const float p = __expf(s[j][r] - mx[r]);
        s[j][r] = p;
        sm[r] += p;
      }
#pragma unroll
    for (int r = 0; r < 4; r++) {
      float ss = sm[r];
      ss += __shfl_xor(ss, 1);
      ss += __shfl_xor(ss, 2);
      ss += __shfl_xor(ss, 4);
      ss += __shfl_xor(ss, 8);
      sm[r] = 1.0f / ss;
    }
    fx4 oacc[4] = {};
#pragma unroll
    for (int c = 0; c < 4; c++) {
      const int nj = (c < 3) ? 6 : 4;
#pragma unroll
      for (int j = 0; j < 6; j++) {
        if (j < nj) {
#pragma unroll
          for (int r = 0; r < 4; r++)
            Pl[wv][lg * 4 + r][j * 16 + lr] = f2bf(s[c * 6 + j][r] * sm[r]);
        }
      }
      const int nk = (c < 3) ? 3 : 2;
#pragma unroll
      for (int ks = 0; ks < 3; ks++) {
        if (ks < nk) {
          short8 pb = *(const short8*)&Pl[wv][lr][ks * 32 + lg * 8];
#pragma unroll
          for (int mi = 0; mi < 4; mi++) {
            short8 vva = *(const short8*)&Vt[mi * 16 + lr][c * 96 + ks * 32 + lg * 8];
            oacc[mi] = MFMA16(vva, pb, oacc[mi]);
          }
        }
      }
    }
    if (qr < 343) {
#pragma unroll
      for (int mi = 0; mi < 4; mi++)
#pragma unroll
        for (int r = 0; r < 4; r++) {
          const int dh = mi * 16 + lg * 4 + r;
          obuf[(size_t)(b * 343 + qr) * 512 + h * 64 + dh] = f2bf(oacc[mi][r]);
        }
    }
  }
}

extern "C" void kernel_launch(void* const* d_in, const int* in_sizes, int n_in,
                              void* d_out, int out_size, void* d_ws, size_t ws_size,
                              hipStream_t stream) {
  const float* x_in = (const float*)d_in[0];
  const float* Wq = (const float*)d_in[1];
  const float* Wk = (const float*)d_in[2];
  const float* Wv = (const float*)d_in[3];
  const float* Wo = (const float*)d_in[4];
  const float* W1 = (const float*)d_in[5];
  const float* b1 = (const float*)d_in[6];
  const float* W2 = (const float*)d_in[7];
  const float* b2 = (const float*)d_in[8];
  const float* ln1g = (const float*)d_in[9];
  const float* ln1b = (const float*)d_in[10];
  const float* ln2g = (const float*)d_in[11];
  const float* ln2b = (const float*)d_in[12];
  const float* lnfg = (const float*)d_in[13];
  const float* lnfb = (const float*)d_in[14];
  const float* rtab = (const float*)d_in[15];
  const float* cw1 = (const float*)d_in[16];
  const float* cb1 = (const float*)d_in[17];
  const float* cw2 = (const float*)d_in[18];
  const int* ridx = (const int*)d_in[19];
  float* xout = (float*)d_out;

  char* p = (char*)d_ws;
  short* wt = (short*)p;      p += 37748736;   // 6 layers x 3145728 bf16 elems
  short* hbuf = (short*)p;    p += 44957696;   // 43904 x 512 bf16
  char* big = p;              p += 179830784;  // qkv+o during attn, mid during ffn
  short* biasb = (short*)p;   p += 1982464;    // 8*22*11*512 bf16
  float* tt = (float*)p;      p += 70304;      // 2197 x 8 f32
  short* qkvbuf = (short*)big;                  // 43904 x 1536
  short* obuf = (short*)(big + 134873088);      // 43904 x 512
  short* mid = (short*)big;                     // 43904 x 2048

  // relative-position bias (shared across layers), fragment-layout bf16
  cpb_kernel<<<(2197 * 8 + 255) / 256, 256, 0, stream>>>(rtab, cw1, cb1, cw2, tt);
  build_biasfrag<<<(8 * 22 * 11 * 512 + 255) / 256, 256, 0, stream>>>(tt, ridx, biasb);

  // weight convert+transpose (bf16, [N][K])
  for (int l = 0; l < 6; l++) {
    const size_t wl = (size_t)l * 3145728;
    transpose_cvt<<<dim3(8, 8), 256, 0, stream>>>(Wq + (size_t)l * 262144, wt + wl, 512, 512);
    transpose_cvt<<<dim3(8, 8), 256, 0, stream>>>(Wk + (size_t)l * 262144, wt + wl + 262144, 512, 512);
    transpose_cvt<<<dim3(8, 8), 256, 0, stream>>>(Wv + (size_t)l * 262144, wt + wl + 524288, 512, 512);
    transpose_cvt<<<dim3(8, 8), 256, 0, stream>>>(Wo + (size_t)l * 262144, wt + wl + 786432, 512, 512);
    transpose_cvt<<<dim3(8, 32), 256, 0, stream>>>(W1 + (size_t)l * 1048576, wt + wl + 1048576, 512, 2048);
    transpose_cvt<<<dim3(32, 8), 256, 0, stream>>>(W2 + (size_t)l * 1048576, wt + wl + 2097152, 2048, 512);
  }

  for (int l = 0; l < 6; l++) {
    const size_t wl = (size_t)l * 3145728;
    const float* xsrc = (l == 0) ? x_in : xout;
    // attention block
    ln_kernel<true><<<10976, 256, 0, stream>>>(xsrc, ln1g + l * 512, ln1b + l * 512, hbuf);
    gemm_s<0><<<343 * 12, 256, 0, stream>>>(hbuf, wt + wl, 1536, 512, 12, 512, nullptr, nullptr, qkvbuf);
    attn_kernel<<<1024, 512, 0, stream>>>(qkvbuf, biasb, obuf);
    gemm_s<1><<<343 * 4, 256, 0, stream>>>(obuf, wt + wl + 786432, 512, 512, 4, 0, nullptr, xsrc, xout);
    // ffn block
    ln_kernel<true><<<10976, 256, 0, stream>>>(xout, ln2g + l * 512, ln2b + l * 512, hbuf);
    gemm_s<2><<<343 * 16, 256, 0, stream>>>(hbuf, wt + wl + 1048576, 2048, 512, 16, 0, b1 + l * 2048, nullptr, mid);
    gemm_s<3><<<343 * 4, 256, 0, stream>>>(mid, wt + wl + 2097152, 512, 2048, 4, 0, b2 + l * 512, xout, xout);
  }
  ln_kernel<false><<<10976, 256, 0, stream>>>(xout, lnfg, lnfb, xout);
}

// Round 10
// 4068.577 us; speedup vs baseline: 1.0540x; 1.0540x over previous
//
#include <hip/hip_runtime.h>

typedef __attribute__((ext_vector_type(8))) short short8;
typedef __attribute__((ext_vector_type(4))) float fx4;
typedef __attribute__((ext_vector_type(4))) int ix4;

#define MFMA16(a, b, c) __builtin_amdgcn_mfma_f32_16x16x32_bf16((a), (b), (c), 0, 0, 0)

__device__ __forceinline__ short f2bf(float f) {
  unsigned u = __float_as_uint(f);
  u += 0x7fffu + ((u >> 16) & 1u);
  return (short)(u >> 16);
}
__device__ __forceinline__ float bf2f(short v) {
  return __uint_as_float(((unsigned)(unsigned short)v) << 16);
}
__device__ __forceinline__ void glds16(const short* g, short* l) {
  __builtin_amdgcn_global_load_lds((const __attribute__((address_space(1))) void*)g,
                                   (__attribute__((address_space(3))) void*)l, 16, 0, 0);
}
__device__ __forceinline__ unsigned lds_off(const void* p) {
  return (unsigned)(uintptr_t)(const __attribute__((address_space(3))) void*)p;
}
// raw ds_read_b128: invisible to the compiler's vmcnt alias tracking --
// ordering handled by explicit lgkmcnt + sched_barrier (rule #18).
__device__ __forceinline__ ix4 ds_read128(unsigned addr) {
  ix4 r;
  asm volatile("ds_read_b128 %0, %1" : "=v"(r) : "v"(addr));
  return r;
}

// ---------- transpose + convert: W [K][N] f32 -> Wt [N][K] bf16 ----------
__global__ __launch_bounds__(256)
void transpose_cvt(const float* __restrict__ W, short* __restrict__ Wt, int K, int N) {
  __shared__ float tile[64][65];
  const int kb = blockIdx.x * 64, nb = blockIdx.y * 64;
  const int t = threadIdx.x;
  const int tr = t >> 6, tc = t & 63;
#pragma unroll 4
  for (int i = 0; i < 16; i++) {
    int r = i * 4 + tr;
    tile[r][tc] = W[(size_t)(kb + r) * N + nb + tc];
  }
  __syncthreads();
#pragma unroll 4
  for (int i = 0; i < 16; i++) {
    int r = i * 4 + tr;
    Wt[(size_t)(nb + r) * K + kb + tc] = f2bf(tile[tc][r]);
  }
}

// ---------- CPB MLP: t[row][h] = relu(rt[row] @ w1 + b1) @ w2 ----------
__global__ __launch_bounds__(256)
void cpb_kernel(const float* __restrict__ rt, const float* __restrict__ w1,
                const float* __restrict__ b1, const float* __restrict__ w2,
                float* __restrict__ tt) {
  const int id = blockIdx.x * 256 + threadIdx.x;
  if (id >= 2197 * 8) return;
  const int row = id >> 3, hh = id & 7;
  float r[8];
#pragma unroll
  for (int i = 0; i < 8; i++) r[i] = rt[row * 8 + i];
  float acc = 0.0f;
  for (int c = 0; c < 512; c++) {
    float s = b1[c];
#pragma unroll
    for (int i = 0; i < 8; i++) s += r[i] * w1[i * 512 + c];
    s = fmaxf(s, 0.0f);
    acc += s * w2[c * 8 + hh];
  }
  tt[id] = acc;
}

// ---------- bias -> MFMA-fragment layout, bf16, pre-masked with -1e30 ----
__global__ __launch_bounds__(256)
void build_biasfrag(const float* __restrict__ tt, const int* __restrict__ ridx,
                    short* __restrict__ biasb) {
  const int id = blockIdx.x * 256 + threadIdx.x;
  if (id >= 8 * 22 * 11 * 512) return;
  const int e = id & 7;
  const int lane = (id >> 3) & 63;
  const int rest = id >> 9;
  const int jp = rest % 11;
  const int rest2 = rest / 11;
  const int qt = rest2 % 22;
  const int h = rest2 / 22;
  const int q = qt * 16 + ((lane >> 4) << 2) + (e & 3);
  const int tok = (jp * 2 + (e >> 2)) * 16 + (lane & 15);
  float val = -1e30f;
  if (q < 343 && tok < 343) val = tt[ridx[q * 343 + tok] * 8 + h];
  biasb[id] = f2bf(val);
}

// ---------- LayerNorm: one wave per row of 512 ----------
template <bool BF16OUT>
__global__ __launch_bounds__(256)
void ln_kernel(const float* x, const float* __restrict__ g,
               const float* __restrict__ bb, void* out) {
  const int row = blockIdx.x * 4 + (threadIdx.x >> 6);
  const int lane = threadIdx.x & 63;
  const float* xr = x + (size_t)row * 512 + lane * 8;
  fx4 va = *(const fx4*)xr;
  fx4 vb = *(const fx4*)(xr + 4);
  float s = va[0] + va[1] + va[2] + va[3] + vb[0] + vb[1] + vb[2] + vb[3];
#pragma unroll
  for (int d = 1; d < 64; d <<= 1) s += __shfl_xor(s, d);
  const float mu = s * (1.0f / 512.0f);
  float v[8];
#pragma unroll
  for (int i = 0; i < 4; i++) { v[i] = va[i] - mu; v[4 + i] = vb[i] - mu; }
  float s2 = 0.0f;
#pragma unroll
  for (int i = 0; i < 8; i++) s2 += v[i] * v[i];
#pragma unroll
  for (int d = 1; d < 64; d <<= 1) s2 += __shfl_xor(s2, d);
  const float rs = rsqrtf(s2 * (1.0f / 512.0f) + 1e-5f);
  fx4 ga = *(const fx4*)(g + lane * 8);
  fx4 gb = *(const fx4*)(g + lane * 8 + 4);
  fx4 ba = *(const fx4*)(bb + lane * 8);
  fx4 b2 = *(const fx4*)(bb + lane * 8 + 4);
  float o[8];
#pragma unroll
  for (int i = 0; i < 4; i++) {
    o[i] = v[i] * rs * ga[i] + ba[i];
    o[4 + i] = v[4 + i] * rs * gb[i] + b2[i];
  }
  if (BF16OUT) {
    short8 ov;
#pragma unroll
    for (int i = 0; i < 8; i++) ov[i] = f2bf(o[i]);
    *(short8*)((short*)out + (size_t)row * 512 + lane * 8) = ov;
  } else {
    float* op = (float*)out + (size_t)row * 512 + lane * 8;
    fx4 o1, o2;
#pragma unroll
    for (int i = 0; i < 4; i++) { o1[i] = o[i]; o2[i] = o[4 + i]; }
    *(fx4*)op = o1;
    *(fx4*)(op + 4) = o2;
  }
}

// ---------- 128x128 bf16 GEMM, BK=32, 3-buf pipeline, ASM ds_read --------
// Round-9 finding: compiler inserted vmcnt(0) before its ds_reads (alias vs
// glds writes to same LDS array) -> every K-step paid full HBM latency
// (T~1200cy, MfmaUtil 19%). Fix: fragment loads via inline-asm ds_read_b128
// (outside alias tracking); explicit vmcnt(4) is now the only VMEM gate.
// Order: vmcnt(4) -> s_barrier -> STAGE(k+2) -> asm ds_read x8 ->
// lgkmcnt(0)+sched_barrier(0) -> 16 MFMA. st_16x32 swizzle kept (0-conflict).
// EPI 0: bf16 out, *0.125 where col<scaleN (fused QKV)
// EPI 1: f32 out = xres + acc                     (O-proj residual)
// EPI 2: bf16 out = gelu_tanh(acc + bias[col])    (FFN1, rcp-based)
// EPI 3: f32 out = xres + acc + bias[col]         (FFN2 residual)
template <int EPI>
__global__ __launch_bounds__(256, 3)
void gemm_s(const short* __restrict__ A, const short* __restrict__ Bt,
            int N, int K, int nbn, int scaleN,
            const float* __restrict__ bias, const float* xres, void* out) {
  __shared__ short Al[3][4096];  // 3 x [8 chunks][16r x 32c swizzled]
  __shared__ short Bl[3][4096];
  const int nwg = gridDim.x;
  const int orig = blockIdx.x;
  const int qq = nwg >> 3, rr = nwg & 7, xc = orig & 7, o8 = orig >> 3;
  const int wgid = (xc < rr ? xc * (qq + 1) : rr * (qq + 1) + (xc - rr) * qq) + o8;
  const int m0 = (wgid / nbn) * 128, n0 = (wgid % nbn) * 128;
  const int t = threadIdx.x, lane = t & 63, wv = t >> 6;
  const int wm = (wv >> 1) * 64, wn = (wv & 1) * 64;
  const int lr = lane & 15, lg = lane >> 4;
  // staging: wave wv owns chunks {2wv, 2wv+1} (rows wv*32 .. wv*32+32)
  const int scol = ((lane & 3) * 8) ^ ((lane & 32) ? 16 : 0);  // pre-swizzled src col
  const int srow = lane >> 2;                                  // 0..15 within chunk
  const short* ag0 = A + (size_t)(m0 + wv * 32 + srow) * K + scol;
  const short* ag1 = A + (size_t)(m0 + wv * 32 + 16 + srow) * K + scol;
  const short* bg0 = Bt + (size_t)(n0 + wv * 32 + srow) * K + scol;
  const short* bg1 = Bt + (size_t)(n0 + wv * 32 + 16 + srow) * K + scol;
  // fragment read byte-offsets (swizzled): frag i == chunk (wave_m*4+i)
  const int cswz = (lg * 8) ^ ((lr & 8) ? 16 : 0);
  const unsigned abase = lds_off(&Al[0][0]);
  const unsigned bbase = lds_off(&Bl[0][0]);
  unsigned aoffB[4], boffB[4];
#pragma unroll
  for (int i = 0; i < 4; i++) {
    aoffB[i] = (((wv >> 1) * 4 + i) * 512 + lr * 32 + cswz) * 2u;
    boffB[i] = (((wv & 1) * 4 + i) * 512 + lr * 32 + cswz) * 2u;
  }
  fx4 acc[4][4] = {};
#define STAGE(KT, BUF)                              \
  do {                                              \
    const int off_ = (KT) * 32;                     \
    short* la_ = &Al[BUF][wv * 1024];               \
    short* lb_ = &Bl[BUF][wv * 1024];               \
    glds16(ag0 + off_, la_);                        \
    glds16(ag1 + off_, la_ + 512);                  \
    glds16(bg0 + off_, lb_);                        \
    glds16(bg1 + off_, lb_ + 512);                  \
  } while (0)
  const int nkt = K >> 5;
  STAGE(0, 0);
  STAGE(1, 1);
  int rb = 0;  // read-buffer index, kt % 3
  for (int kt = 0; kt < nkt; kt++) {
    if (kt + 1 < nkt)
      asm volatile("s_waitcnt vmcnt(4)" ::: "memory");  // own stage-k loads done
    else
      asm volatile("s_waitcnt vmcnt(0)" ::: "memory");  // final drain
    __builtin_amdgcn_s_barrier();  // all waves' stage-k data now in LDS
    if (kt + 2 < nkt) {
      int sb = rb + 2;
      if (sb >= 3) sb -= 3;
      STAGE(kt + 2, sb);  // stays in flight across next barrier
    }
    const unsigned ab = abase + (unsigned)rb * 8192u;
    const unsigned bb_ = bbase + (unsigned)rb * 8192u;
    ix4 ar[4], br[4];
#pragma unroll
    for (int i = 0; i < 4; i++) ar[i] = ds_read128(ab + aoffB[i]);
#pragma unroll
    for (int i = 0; i < 4; i++) br[i] = ds_read128(bb_ + boffB[i]);
    asm volatile("s_waitcnt lgkmcnt(0)" ::: "memory");
    __builtin_amdgcn_sched_barrier(0);  // rule #18: pin MFMAs after the wait
#pragma unroll
    for (int mi = 0; mi < 4; mi++) {
      const short8 af = __builtin_bit_cast(short8, ar[mi]);
#pragma unroll
      for (int ni = 0; ni < 4; ni++)
        acc[mi][ni] = MFMA16(af, __builtin_bit_cast(short8, br[ni]), acc[mi][ni]);
    }
    rb = (rb + 1 < 3) ? rb + 1 : 0;
  }
#undef STAGE
#pragma unroll
  for (int mi = 0; mi < 4; mi++) {
#pragma unroll
    for (int ni = 0; ni < 4; ni++) {
#pragma unroll
      for (int r = 0; r < 4; r++) {
        const int row = m0 + wm + mi * 16 + lg * 4 + r;
        const int col = n0 + wn + ni * 16 + lr;
        const float vacc = acc[mi][ni][r];
        const size_t idx = (size_t)row * N + col;
        if (EPI == 0) {
          const float sc = (col < scaleN) ? 0.125f : 1.0f;
          ((short*)out)[idx] = f2bf(vacc * sc);
        } else if (EPI == 1) {
          ((float*)out)[idx] = xres[idx] + vacc;
        } else if (EPI == 2) {
          const float v = vacc + bias[col];
          const float tt = v * v;
          const float u2 = v * fmaf(tt, -0.0713548165f, -1.5957691216f);  // -2u
          const float g = v * __builtin_amdgcn_rcpf(1.0f + __expf(u2));
          ((short*)out)[idx] = f2bf(g);
        } else {
          ((float*)out)[idx] = xres[idx] + vacc + bias[col];
        }
      }
    }
  }
}

// ---------- fused windowed attention v3: block=(b,h), 512 thr, 8 waves ---
__global__ __launch_bounds__(512, 1)
void attn_kernel(const short* __restrict__ qkv, const short* __restrict__ biasb,
                 short* __restrict__ obuf) {
  __shared__ short Kl[352][72];
  __shared__ short Vt[64][360];
  __shared__ short Pl[8][16][96];
  const int b = blockIdx.x >> 3, h = blockIdx.x & 7;
  const int t = threadIdx.x, lane = t & 63, wv = t >> 6;
  const int lr = lane & 15, lg = lane >> 4;
  const size_t base = (size_t)b * 343 * 1536 + h * 64;
  const short* qg = qkv + base;
  const short* kg = qkv + base + 512;
  const short* vg = qkv + base + 1024;
  for (int c = t; c < 352 * 8; c += 512) {
    const int tok = c >> 3, d8 = (c & 7) * 8;
    const int ts = tok < 343 ? tok : 342;
    short8 kvv = *(const short8*)(kg + (size_t)ts * 1536 + d8);
    short8 vvv = *(const short8*)(vg + (size_t)ts * 1536 + d8);
    *(short8*)&Kl[tok][d8] = kvv;
#pragma unroll
    for (int j = 0; j < 8; j++) Vt[d8 + j][tok] = vvv[j];
  }
  __syncthreads();
  for (int qt = wv; qt < 22; qt += 8) {
    const int q0 = qt * 16;
    const int qr = q0 + lr;
    const int qs = qr < 343 ? qr : 342;
    short8 qf0 = *(const short8*)(qg + (size_t)qs * 1536 + lg * 8);
    short8 qf1 = *(const short8*)(qg + (size_t)qs * 1536 + 32 + lg * 8);
    fx4 s[22];
#pragma unroll
    for (int j = 0; j < 22; j++) {
      short8 kf0 = *(const short8*)&Kl[j * 16 + lr][lg * 8];
      short8 kf1 = *(const short8*)&Kl[j * 16 + lr][32 + lg * 8];
      fx4 z = {0.0f, 0.0f, 0.0f, 0.0f};
      z = MFMA16(qf0, kf0, z);
      z = MFMA16(qf1, kf1, z);
      s[j] = z;
    }
    const short* bp = biasb + (size_t)((h * 22 + qt) * 11) * 512 + lane * 8;
#pragma unroll
    for (int jp = 0; jp < 11; jp++) {
      short8 bb = *(const short8*)(bp + jp * 512);
#pragma unroll
      for (int r = 0; r < 4; r++) {
        s[2 * jp][r] += bf2f(bb[r]);
        s[2 * jp + 1][r] += bf2f(bb[4 + r]);
      }
    }
    float mx[4] = {-1e30f, -1e30f, -1e30f, -1e30f};
#pragma unroll
    for (int j = 0; j < 22; j++)
#pragma unroll
      for (int r = 0; r < 4; r++) mx[r] = fmaxf(mx[r], s[j][r]);
#pragma unroll
    for (int r = 0; r < 4; r++) {
      float m = mx[r];
      m = fmaxf(m, __shfl_xor(m, 1));
      m = fmaxf(m, __shfl_xor(m, 2));
      m = fmaxf(m, __shfl_xor(m, 4));
      m = fmaxf(m, __shfl_xor(m, 8));
      mx[r] = m;
    }
    float sm[4] = {0.0f, 0.0f, 0.0f, 0.0f};
#pragma unroll
    for (int j = 0; j < 22; j++)
#pragma unroll
      for (int r = 0; r < 4; r++) {
        const float p = __expf(s[j][r] - mx[r]);
        s[j][r] = p;
        sm[r] += p;
      }
#pragma unroll
    for (int r = 0; r < 4; r++) {
      float ss = sm[r];
      ss += __shfl_xor(ss, 1);
      ss += __shfl_xor(ss, 2);
      ss += __shfl_xor(ss, 4);
      ss += __shfl_xor(ss, 8);
      sm[r] = 1.0f / ss;
    }
    fx4 oacc[4] = {};
#pragma unroll
    for (int c = 0; c < 4; c++) {
      const int nj = (c < 3) ? 6 : 4;
#pragma unroll
      for (int j = 0; j < 6; j++) {
        if (j < nj) {
#pragma unroll
          for (int r = 0; r < 4; r++)
            Pl[wv][lg * 4 + r][j * 16 + lr] = f2bf(s[c * 6 + j][r] * sm[r]);
        }
      }
      const int nk = (c < 3) ? 3 : 2;
#pragma unroll
      for (int ks = 0; ks < 3; ks++) {
        if (ks < nk) {
          short8 pb = *(const short8*)&Pl[wv][lr][ks * 32 + lg * 8];
#pragma unroll
          for (int mi = 0; mi < 4; mi++) {
            short8 vva = *(const short8*)&Vt[mi * 16 + lr][c * 96 + ks * 32 + lg * 8];
            oacc[mi] = MFMA16(vva, pb, oacc[mi]);
          }
        }
      }
    }
    if (qr < 343) {
#pragma unroll
      for (int mi = 0; mi < 4; mi++)
#pragma unroll
        for (int r = 0; r < 4; r++) {
          const int dh = mi * 16 + lg * 4 + r;
          obuf[(size_t)(b * 343 + qr) * 512 + h * 64 + dh] = f2bf(oacc[mi][r]);
        }
    }
  }
}

extern "C" void kernel_launch(void* const* d_in, const int* in_sizes, int n_in,
                              void* d_out, int out_size, void* d_ws, size_t ws_size,
                              hipStream_t stream) {
  const float* x_in = (const float*)d_in[0];
  const float* Wq = (const float*)d_in[1];
  const float* Wk = (const float*)d_in[2];
  const float* Wv = (const float*)d_in[3];
  const float* Wo = (const float*)d_in[4];
  const float* W1 = (const float*)d_in[5];
  const float* b1 = (const float*)d_in[6];
  const float* W2 = (const float*)d_in[7];
  const float* b2 = (const float*)d_in[8];
  const float* ln1g = (const float*)d_in[9];
  const float* ln1b = (const float*)d_in[10];
  const float* ln2g = (const float*)d_in[11];
  const float* ln2b = (const float*)d_in[12];
  const float* lnfg = (const float*)d_in[13];
  const float* lnfb = (const float*)d_in[14];
  const float* rtab = (const float*)d_in[15];
  const float* cw1 = (const float*)d_in[16];
  const float* cb1 = (const float*)d_in[17];
  const float* cw2 = (const float*)d_in[18];
  const int* ridx = (const int*)d_in[19];
  float* xout = (float*)d_out;

  char* p = (char*)d_ws;
  short* wt = (short*)p;      p += 37748736;   // 6 layers x 3145728 bf16 elems
  short* hbuf = (short*)p;    p += 44957696;   // 43904 x 512 bf16
  char* big = p;              p += 179830784;  // qkv+o during attn, mid during ffn
  short* biasb = (short*)p;   p += 1982464;    // 8*22*11*512 bf16
  float* tt = (float*)p;      p += 70304;      // 2197 x 8 f32
  short* qkvbuf = (short*)big;                  // 43904 x 1536
  short* obuf = (short*)(big + 134873088);      // 43904 x 512
  short* mid = (short*)big;                     // 43904 x 2048

  // relative-position bias (shared across layers), fragment-layout bf16
  cpb_kernel<<<(2197 * 8 + 255) / 256, 256, 0, stream>>>(rtab, cw1, cb1, cw2, tt);
  build_biasfrag<<<(8 * 22 * 11 * 512 + 255) / 256, 256, 0, stream>>>(tt, ridx, biasb);

  // weight convert+transpose (bf16, [N][K])
  for (int l = 0; l < 6; l++) {
    const size_t wl = (size_t)l * 3145728;
    transpose_cvt<<<dim3(8, 8), 256, 0, stream>>>(Wq + (size_t)l * 262144, wt + wl, 512, 512);
    transpose_cvt<<<dim3(8, 8), 256, 0, stream>>>(Wk + (size_t)l * 262144, wt + wl + 262144, 512, 512);
    transpose_cvt<<<dim3(8, 8), 256, 0, stream>>>(Wv + (size_t)l * 262144, wt + wl + 524288, 512, 512);
    transpose_cvt<<<dim3(8, 8), 256, 0, stream>>>(Wo + (size_t)l * 262144, wt + wl + 786432, 512, 512);
    transpose_cvt<<<dim3(8, 32), 256, 0, stream>>>(W1 + (size_t)l * 1048576, wt + wl + 1048576, 512, 2048);
    transpose_cvt<<<dim3(32, 8), 256, 0, stream>>>(W2 + (size_t)l * 1048576, wt + wl + 2097152, 2048, 512);
  }

  for (int l = 0; l < 6; l++) {
    const size_t wl = (size_t)l * 3145728;
    const float* xsrc = (l == 0) ? x_in : xout;
    // attention block
    ln_kernel<true><<<10976, 256, 0, stream>>>(xsrc, ln1g + l * 512, ln1b + l * 512, hbuf);
    gemm_s<0><<<343 * 12, 256, 0, stream>>>(hbuf, wt + wl, 1536, 512, 12, 512, nullptr, nullptr, qkvbuf);
    attn_kernel<<<1024, 512, 0, stream>>>(qkvbuf, biasb, obuf);
    gemm_s<1><<<343 * 4, 256, 0, stream>>>(obuf, wt + wl + 786432, 512, 512, 4, 0, nullptr, xsrc, xout);
    // ffn block
    ln_kernel<true><<<10976, 256, 0, stream>>>(xout, ln2g + l * 512, ln2b + l * 512, hbuf);
    gemm_s<2><<<343 * 16, 256, 0, stream>>>(hbuf, wt + wl + 1048576, 2048, 512, 16, 0, b1 + l * 2048, nullptr, mid);
    gemm_s<3><<<343 * 4, 256, 0, stream>>>(mid, wt + wl + 2097152, 512, 2048, 4, 0, b2 + l * 512, xout, xout);
  }
  ln_kernel<false><<<10976, 256, 0, stream>>>(xout, lnfg, lnfb, xout);
}